// Round 11
// baseline (257.546 us; speedup 1.0000x reference)
//
#include <hip/hip_runtime.h>

#define N 2048
#define DIM 64
#define NB 2048
#define PD_RANGE 1024.0f      // fixed hist range; pd <= 4*max||x||^2 ~ 520 << 1024
#define LOG_N 7.624618986159398f

typedef short bf16x8 __attribute__((ext_vector_type(8)));
typedef float f32x4 __attribute__((ext_vector_type(4)));
typedef unsigned short u16x8 __attribute__((ext_vector_type(8)));

// ws layout (bytes)
#define SCAL_OFF  0           // f32[2]: inv_hh, thh (written by hist block)
#define CNTT_OFF  256         // u32[256] per-i-tile fan-in counters (zeroed by prep block 0)
#define SQ_OFF    2048        // f32[2048]
#define XB_OFF    10240       // bf16 XB[N][64] row-major       (262144)
#define WT_OFF    272384      // bf16 WT[16][64][128] (d-major) (262144)
#define XT_OFF    534528      // bf16 XT[16][64][128]           (262144)
#define P1_OFF    796672      // f32 P1[2][2048][64]            (1048576)
#define P2_OFF    1845248     // f32 P2[2][2048][64]            (1048576)
#define RS_OFF    2893824     // f32 RS[2][2048]                (16384)

__device__ inline float wred64(float v) {
    #pragma unroll
    for (int m = 32; m; m >>= 1) v += __shfl_xor(v, m, 64);
    return v;
}
__device__ inline unsigned short f2bf(float f) {
    unsigned u = __float_as_uint(f);
    return (unsigned short)((u + 0x7FFFu + ((u >> 16) & 1u)) >> 16);
}

// ---------------- fused prep (blocks 0-511) + sampled hist/median (block 512) ----------------
__global__ __launch_bounds__(256) void prep_hist_k(const float* __restrict__ x,
                                                   const float* __restrict__ mu,
                                                   char* __restrict__ ws) {
    __shared__ unsigned short s_xi[32 * 64];      // 4 KB (sampled i rows, swizzled)
    __shared__ unsigned short s_xj[64 * 64];      // 8 KB
    __shared__ float s_sqi[32];
    __shared__ float s_sqj[64];
    __shared__ unsigned s_hist[NB];               // 8 KB
    __shared__ unsigned csum[256];
    __shared__ float medv[2];
    int tid = threadIdx.x;

    if (blockIdx.x < 512) {
        // ---- prep path ----
        unsigned short* XB = (unsigned short*)(ws + XB_OFF);
        unsigned short* WT = (unsigned short*)(ws + WT_OFF);
        unsigned short* XT = (unsigned short*)(ws + XT_OFF);
        float* SQ = (float*)(ws + SQ_OFF);
        if (blockIdx.x == 0) ((unsigned*)(ws + CNTT_OFF))[tid] = 0u;
        int w = tid >> 6, lane = tid & 63;
        int j = blockIdx.x * 4 + w;
        float xv = x[j * DIM + lane];
        float sg = mu[lane] - xv;                       // s_grad
        float sq = wred64(xv * xv);
        float xd = wred64(xv * sg);
        float wv = sg - xv * (xd / sq) - xv * (63.0f / sq);  // D_j s_grad + divD_j
        XB[j * DIM + lane] = f2bf(xv);
        int bo = ((j >> 7) * DIM + lane) * 128 + (j & 127);  // [jt][d][jl]
        XT[bo] = f2bf(xv);
        WT[bo] = f2bf(wv);
        if (lane == 0) SQ[j] = sq;
        return;
    }

    // ---- hist path: 32 sampled rows (stride 64) x all 2048 j = 65536 samples ----
    float* scal_f = (float*)(ws + SCAL_OFF);
    for (int b = tid; b < NB; b += 256) s_hist[b] = 0u;
    if (tid < 32) s_sqi[tid] = 0.f;
    __syncthreads();
    {   // stage sampled i rows: r = tid>>3 (0..31), c8 = tid&7
        int r = tid >> 3, c8 = tid & 7;
        const float* src = x + (r * 64) * DIM + c8 * 8;
        float4 v0 = *(const float4*)(src);
        float4 v1 = *(const float4*)(src + 4);
        float pa = v0.x*v0.x + v0.y*v0.y + v0.z*v0.z + v0.w*v0.w
                 + v1.x*v1.x + v1.y*v1.y + v1.z*v1.z + v1.w*v1.w;
        atomicAdd(&s_sqi[r], pa);
        u16x8 b;
        b[0]=f2bf(v0.x); b[1]=f2bf(v0.y); b[2]=f2bf(v0.z); b[3]=f2bf(v0.w);
        b[4]=f2bf(v1.x); b[5]=f2bf(v1.y); b[6]=f2bf(v1.z); b[7]=f2bf(v1.w);
        *(u16x8*)((char*)s_xi + r * 128 + ((c8 * 16) ^ ((r & 7) << 4))) = b;
    }
    __syncthreads();
    int lane = tid & 63, w = tid >> 6, lo = lane & 15, hi = lane >> 4;
    bf16x8 af[2][2];
    #pragma unroll
    for (int it = 0; it < 2; it++)
        #pragma unroll
        for (int kc = 0; kc < 2; kc++) {
            int row = it * 16 + lo;
            af[it][kc] = *(const bf16x8*)((const char*)s_xi + row * 128 +
                          ((kc * 64 + hi * 16) ^ ((row & 7) << 4)));
        }
    const float scale = (float)NB / PD_RANGE;
    for (int jt = 0; jt < 32; jt++) {
        __syncthreads();
        if (tid < 64) s_sqj[tid] = 0.f;
        __syncthreads();
        {   // stage 64 j rows: jr = tid>>2, c16 = (tid&3)*16
            int jr = tid >> 2, c16 = (tid & 3) * 16;
            const float* src = x + (jt * 64 + jr) * DIM + c16;
            float4 v0 = *(const float4*)(src);
            float4 v1 = *(const float4*)(src + 4);
            float4 v2 = *(const float4*)(src + 8);
            float4 v3 = *(const float4*)(src + 12);
            float pa = v0.x*v0.x+v0.y*v0.y+v0.z*v0.z+v0.w*v0.w
                     + v1.x*v1.x+v1.y*v1.y+v1.z*v1.z+v1.w*v1.w
                     + v2.x*v2.x+v2.y*v2.y+v2.z*v2.z+v2.w*v2.w
                     + v3.x*v3.x+v3.y*v3.y+v3.z*v3.z+v3.w*v3.w;
            atomicAdd(&s_sqj[jr], pa);
            u16x8 b0, b1;
            b0[0]=f2bf(v0.x); b0[1]=f2bf(v0.y); b0[2]=f2bf(v0.z); b0[3]=f2bf(v0.w);
            b0[4]=f2bf(v1.x); b0[5]=f2bf(v1.y); b0[6]=f2bf(v1.z); b0[7]=f2bf(v1.w);
            b1[0]=f2bf(v2.x); b1[1]=f2bf(v2.y); b1[2]=f2bf(v2.z); b1[3]=f2bf(v2.w);
            b1[4]=f2bf(v3.x); b1[5]=f2bf(v3.y); b1[6]=f2bf(v3.z); b1[7]=f2bf(v3.w);
            int sw = (jr & 7) << 4;
            *(u16x8*)((char*)s_xj + jr * 128 + ((c16 * 2) ^ sw)) = b0;
            *(u16x8*)((char*)s_xj + jr * 128 + ((c16 * 2 + 16) ^ sw)) = b1;
        }
        __syncthreads();
        bf16x8 bfr[2];
        #pragma unroll
        for (int kc = 0; kc < 2; kc++) {
            int row = w * 16 + lo;
            bfr[kc] = *(const bf16x8*)((const char*)s_xj + row * 128 +
                       ((kc * 64 + hi * 16) ^ ((row & 7) << 4)));
        }
        f32x4 acc[2]; acc[0] = (f32x4)0.f; acc[1] = (f32x4)0.f;
        #pragma unroll
        for (int it = 0; it < 2; it++)
            #pragma unroll
            for (int kc = 0; kc < 2; kc++)
                acc[it] = __builtin_amdgcn_mfma_f32_16x16x32_bf16(af[it][kc], bfr[kc], acc[it], 0, 0, 0);
        #pragma unroll
        for (int it = 0; it < 2; it++)
            #pragma unroll
            for (int r = 0; r < 4; r++) {
                int i_s = it * 16 + hi * 4 + r;
                int j_l = w * 16 + lo;
                float pd = fmaxf(s_sqi[i_s] + s_sqj[j_l] - 2.0f * acc[it][r], 0.0f);
                int bin = min((int)(pd * scale), NB - 1);
                atomicAdd(&s_hist[bin], 1u);
            }
    }
    __syncthreads();
    // ---- median scan: 65536 samples -> kq {32767, 32768} ----
    unsigned v[8]; unsigned s = 0;
    #pragma unroll
    for (int b = 0; b < 8; b++) { v[b] = s_hist[tid * 8 + b]; s += v[b]; }
    csum[tid] = s;
    __syncthreads();
    #pragma unroll
    for (int off = 1; off < 256; off <<= 1) {
        unsigned t = (tid >= off) ? csum[tid - off] : 0u;
        __syncthreads();
        csum[tid] += t;
        __syncthreads();
    }
    unsigned incl = csum[tid], excl = incl - s;
    const float binw = PD_RANGE / (float)NB;
    const unsigned kqs[2] = { 32767u, 32768u };
    #pragma unroll
    for (int t = 0; t < 2; t++) {
        unsigned kq = kqs[t];
        if (excl <= kq && kq < incl) {
            unsigned a2 = excl; int bin = -1;
            #pragma unroll
            for (int b = 0; b < 8; b++) {
                unsigned na = a2 + v[b];
                if (bin < 0 && na > kq) bin = tid * 8 + b;
                a2 = na;
            }
            medv[t] = ((float)bin + 0.5f) * binw;
        }
    }
    __syncthreads();
    if (tid == 0) {
        float hh = 0.5f * (medv[0] + medv[1]) / LOG_N + 1e-6f;
        scal_f[0] = 1.0f / hh;
        scal_f[1] = 2.0f / hh;
    }
}

// ---------------- fused SVGD: j-half per block, plain-store fan-in epilogue ----------------
__global__ __launch_bounds__(512, 4) void svgd_k(const float* __restrict__ x,
                                                 char* __restrict__ ws,
                                                 float* __restrict__ out) {
    __shared__ unsigned short s_k[16 * 256];     // 8 KB (intra-wave K shuffle)
    __shared__ unsigned short s_c[16 * 256];     // 8 KB
    __shared__ float s_red[2 * 8 * 64];          // 4 KB (cross-wave reduction)
    __shared__ float s_rs[8];
    __shared__ unsigned s_flag;
    const unsigned short* XB = (const unsigned short*)(ws + XB_OFF);
    const char* WTb = ws + WT_OFF;
    const char* XTb = ws + XT_OFF;
    const float* SQ = (const float*)(ws + SQ_OFF);
    const float* scal_f = (const float*)(ws + SCAL_OFF);
    float* P1 = (float*)(ws + P1_OFF);
    float* P2 = (float*)(ws + P2_OFF);
    float* RS = (float*)(ws + RS_OFF);
    unsigned* cntt = (unsigned*)(ws + CNTT_OFF);
    int tid = threadIdx.x;
    int it = blockIdx.x >> 1, jh = blockIdx.x & 1;
    int i0 = it * 8;
    int lane = tid & 63, w = tid >> 6, lo = lane & 15, hi = lane >> 4;

    for (int q = tid; q < 2 * 8 * 64; q += 512) s_red[q] = 0.f;
    if (tid < 8) s_rs[tid] = 0.f;

    float inv_hh = scal_f[0], thh = scal_f[1];
    float sqi_r[4];
    #pragma unroll
    for (int r = 0; r < 4; r++) { int il = hi * 4 + r; sqi_r[r] = (il < 8) ? SQ[i0 + il] : 0.0f; }
    bf16x8 af[2];
    #pragma unroll
    for (int kc = 0; kc < 2; kc++)
        af[kc] = (lo < 8) ? *(const bf16x8*)(XB + (i0 + lo) * 64 + kc * 32 + hi * 8) : (bf16x8)0;

    f32x4 a1[4], a2[4], rsv;
    #pragma unroll
    for (int sd = 0; sd < 4; sd++) { a1[sd] = (f32x4)0.f; a2[sd] = (f32x4)0.f; }
    rsv = (f32x4)0.f;
    bf16x8 ones;
    #pragma unroll
    for (int e = 0; e < 8; e++) ones[e] = (short)0x3F80;
    __syncthreads();                              // s_red init visible

    // ---- 4 iters x 256 j (8 waves x 32 j) over this j-half ----
    for (int itr = 0; itr < 4; itr++) {
        int jw = jh * 1024 + itr * 256 + w * 32;
        bf16x8 bS[2][2];
        #pragma unroll
        for (int sj = 0; sj < 2; sj++)
            #pragma unroll
            for (int kc = 0; kc < 2; kc++)
                bS[sj][kc] = *(const bf16x8*)(XB + (jw + sj * 16 + lo) * 64 + kc * 32 + hi * 8);
        float sqj[2];
        sqj[0] = SQ[jw + lo];
        sqj[1] = SQ[jw + 16 + lo];
        int jt = jw >> 7;
        const char* wtb = WTb + jt * 16384;
        const char* xtb = XTb + jt * 16384;
        bf16x8 bW[4], bX[4];
        #pragma unroll
        for (int sd = 0; sd < 4; sd++) {
            int off = (sd * 16 + lo) * 256 + ((jw & 127) * 2) + hi * 16;
            bW[sd] = *(const bf16x8*)(wtb + off);
            bX[sd] = *(const bf16x8*)(xtb + off);
        }
        // S = X_I . X_J^T
        f32x4 sreg[2]; sreg[0] = (f32x4)0.f; sreg[1] = (f32x4)0.f;
        #pragma unroll
        for (int kc = 0; kc < 2; kc++)
            #pragma unroll
            for (int sj = 0; sj < 2; sj++)
                sreg[sj] = __builtin_amdgcn_mfma_f32_16x16x32_bf16(af[kc], bS[sj][kc], sreg[sj], 0, 0, 0);
        // K, C -> bf16 -> LDS (intra-wave re-layout; read window == write window per wave)
        #pragma unroll
        for (int sj = 0; sj < 2; sj++) {
            float rq = 1.0f / sqj[sj];
            #pragma unroll
            for (int r = 0; r < 4; r++) {
                int il = hi * 4 + r;
                float dot = sreg[sj][r];
                float pd = fmaxf(sqi_r[r] + sqj[sj] - 2.0f * dot, 0.0f);
                float kv = __expf(-pd * inv_hh);
                float cv = kv * dot * rq;
                int byt = (w * 64 + sj * 32 + lo * 2) ^ ((il & 7) << 4);
                *(unsigned short*)((char*)s_k + il * 512 + byt) = f2bf(kv);
                *(unsigned short*)((char*)s_c + il * 512 + byt) = f2bf(cv);
            }
        }
        int bytK = (w * 64 + hi * 16) ^ ((lo & 7) << 4);
        bf16x8 aK = *(const bf16x8*)((const char*)s_k + lo * 512 + bytK);
        bf16x8 aC = *(const bf16x8*)((const char*)s_c + lo * 512 + bytK);
        // acc1 += K.W, acc2 += C.X, rs += K.1
        #pragma unroll
        for (int sd = 0; sd < 4; sd++) {
            a1[sd] = __builtin_amdgcn_mfma_f32_16x16x32_bf16(aK, bW[sd], a1[sd], 0, 0, 0);
            a2[sd] = __builtin_amdgcn_mfma_f32_16x16x32_bf16(aC, bX[sd], a2[sd], 0, 0, 0);
        }
        rsv = __builtin_amdgcn_mfma_f32_16x16x32_bf16(aK, ones, rsv, 0, 0, 0);
    }

    // ---- cross-wave reduction (8 waves' disjoint j-slices) ----
    #pragma unroll
    for (int sd = 0; sd < 4; sd++)
        #pragma unroll
        for (int r = 0; r < 4; r++) {
            int il = hi * 4 + r;
            if (il < 8) {
                int dd = sd * 16 + lo;
                atomicAdd(&s_red[il * 64 + dd], a1[sd][r]);
                atomicAdd(&s_red[8 * 64 + il * 64 + dd], a2[sd][r]);
            }
        }
    if (lo == 0) {
        #pragma unroll
        for (int r = 0; r < 4; r++) {
            int il = hi * 4 + r;
            if (il < 8) atomicAdd(&s_rs[il], rsv[r]);
        }
    }
    __syncthreads();

    // ---- plain-store partials for this j-half ----
    for (int q = tid; q < 8 * 64; q += 512) {
        int row = q >> 6, dd = q & 63;
        P1[(jh * N + i0 + row) * 64 + dd] = s_red[q];
        P2[(jh * N + i0 + row) * 64 + dd] = s_red[8 * 64 + q];
    }
    if (tid < 8) RS[jh * N + i0 + tid] = s_rs[tid];

    // ---- 2-way fan-in: second arriver combines halves + epilogue ----
    __threadfence();
    if (tid == 0) s_flag = atomicAdd(&cntt[it], 1u);
    __syncthreads();
    if (s_flag == 1u) {
        __threadfence();
        int row = i0 + w;                          // 8 waves x 1 row
        float xv = x[row * DIM + lane];
        float sqi = SQ[row];
        float acc1 = P1[row * 64 + lane] + P1[(N + row) * 64 + lane];
        float acc2 = P2[row * 64 + lane] + P2[(N + row) * 64 + lane];
        float rs = RS[row] + RS[N + row];
        float inner = acc1 + (rs * xv - acc2) * thh;
        float xin = wred64(xv * inner);
        float gr = inner - xv * ((xin + 63.0f) / sqi);
        float dx = gr * (0.1f / (float)N);
        dx = fminf(fmaxf(dx, -1000.0f), 1000.0f);
        out[row * DIM + lane] = xv + dx;
    }
}

extern "C" void kernel_launch(void* const* d_in, const int* in_sizes, int n_in,
                              void* d_out, int out_size, void* d_ws, size_t ws_size,
                              hipStream_t stream) {
    const float* x  = (const float*)d_in[0];
    const float* mu = (const float*)d_in[1];
    float* out = (float*)d_out;
    char* ws = (char*)d_ws;

    prep_hist_k<<<513, 256, 0, stream>>>(x, mu, ws);
    svgd_k<<<(N / 8) * 2, 512, 0, stream>>>(x, ws, out);
}

// Round 13
// 139.877 us; speedup vs baseline: 1.8412x; 1.8412x over previous
//
#include <hip/hip_runtime.h>

#define N 2048
#define DIM 64
#define NB 2048
#define PD_RANGE 1024.0f      // fixed hist range; pd <= 4*max||x||^2 ~ 520 << 1024
#define LOG_N 7.624618986159398f

typedef short bf16x8 __attribute__((ext_vector_type(8)));
typedef float f32x4 __attribute__((ext_vector_type(4)));
typedef unsigned short u16x8 __attribute__((ext_vector_type(8)));

// ws layout (bytes)
#define SCAL_OFF  0           // f32[2]: inv_hh, thh (written by hist block)
#define SQ_OFF    2048        // f32[2048]
#define XB_OFF    10240       // bf16 XB[N][64] row-major       (262144)
#define WT_OFF    272384      // bf16 WT[16][64][128] (d-major) (262144)
#define XT_OFF    534528      // bf16 XT[16][64][128]           (262144)

__device__ inline float wred64(float v) {
    #pragma unroll
    for (int m = 32; m; m >>= 1) v += __shfl_xor(v, m, 64);
    return v;
}
__device__ inline unsigned short f2bf(float f) {
    unsigned u = __float_as_uint(f);
    return (unsigned short)((u + 0x7FFFu + ((u >> 16) & 1u)) >> 16);
}

// ---------------- fused prep (blocks 0-511) + sampled hist/median (block 512) ----------------
__global__ __launch_bounds__(256) void prep_hist_k(const float* __restrict__ x,
                                                   const float* __restrict__ mu,
                                                   char* __restrict__ ws) {
    __shared__ unsigned short s_xi[32 * 64];      // 4 KB (sampled i rows, swizzled)
    __shared__ unsigned short s_xj[64 * 64];      // 8 KB
    __shared__ float s_sqi[32];
    __shared__ float s_sqj[64];
    __shared__ unsigned s_hist[NB];               // 8 KB
    __shared__ unsigned csum[256];
    __shared__ float medv[2];
    int tid = threadIdx.x;

    if (blockIdx.x < 512) {
        // ---- prep path ----
        unsigned short* XB = (unsigned short*)(ws + XB_OFF);
        unsigned short* WT = (unsigned short*)(ws + WT_OFF);
        unsigned short* XT = (unsigned short*)(ws + XT_OFF);
        float* SQ = (float*)(ws + SQ_OFF);
        int w = tid >> 6, lane = tid & 63;
        int j = blockIdx.x * 4 + w;
        float xv = x[j * DIM + lane];
        float sg = mu[lane] - xv;                       // s_grad
        float sq = wred64(xv * xv);
        float xd = wred64(xv * sg);
        float wv = sg - xv * (xd / sq) - xv * (63.0f / sq);  // D_j s_grad + divD_j
        XB[j * DIM + lane] = f2bf(xv);
        int bo = ((j >> 7) * DIM + lane) * 128 + (j & 127);  // [jt][d][jl]
        XT[bo] = f2bf(xv);
        WT[bo] = f2bf(wv);
        if (lane == 0) SQ[j] = sq;
        return;
    }

    // ---- hist path: 32 sampled rows (stride 64) x all 2048 j = 65536 samples ----
    float* scal_f = (float*)(ws + SCAL_OFF);
    for (int b = tid; b < NB; b += 256) s_hist[b] = 0u;
    if (tid < 32) s_sqi[tid] = 0.f;
    __syncthreads();
    {   // stage sampled i rows: r = tid>>3 (0..31), c8 = tid&7
        int r = tid >> 3, c8 = tid & 7;
        const float* src = x + (r * 64) * DIM + c8 * 8;
        float4 v0 = *(const float4*)(src);
        float4 v1 = *(const float4*)(src + 4);
        float pa = v0.x*v0.x + v0.y*v0.y + v0.z*v0.z + v0.w*v0.w
                 + v1.x*v1.x + v1.y*v1.y + v1.z*v1.z + v1.w*v1.w;
        atomicAdd(&s_sqi[r], pa);
        u16x8 b;
        b[0]=f2bf(v0.x); b[1]=f2bf(v0.y); b[2]=f2bf(v0.z); b[3]=f2bf(v0.w);
        b[4]=f2bf(v1.x); b[5]=f2bf(v1.y); b[6]=f2bf(v1.z); b[7]=f2bf(v1.w);
        *(u16x8*)((char*)s_xi + r * 128 + ((c8 * 16) ^ ((r & 7) << 4))) = b;
    }
    __syncthreads();
    int lane = tid & 63, w = tid >> 6, lo = lane & 15, hi = lane >> 4;
    bf16x8 af[2][2];
    #pragma unroll
    for (int it = 0; it < 2; it++)
        #pragma unroll
        for (int kc = 0; kc < 2; kc++) {
            int row = it * 16 + lo;
            af[it][kc] = *(const bf16x8*)((const char*)s_xi + row * 128 +
                          ((kc * 64 + hi * 16) ^ ((row & 7) << 4)));
        }
    const float scale = (float)NB / PD_RANGE;
    for (int jt = 0; jt < 32; jt++) {
        __syncthreads();
        if (tid < 64) s_sqj[tid] = 0.f;
        __syncthreads();
        {   // stage 64 j rows: jr = tid>>2, c16 = (tid&3)*16
            int jr = tid >> 2, c16 = (tid & 3) * 16;
            const float* src = x + (jt * 64 + jr) * DIM + c16;
            float4 v0 = *(const float4*)(src);
            float4 v1 = *(const float4*)(src + 4);
            float4 v2 = *(const float4*)(src + 8);
            float4 v3 = *(const float4*)(src + 12);
            float pa = v0.x*v0.x+v0.y*v0.y+v0.z*v0.z+v0.w*v0.w
                     + v1.x*v1.x+v1.y*v1.y+v1.z*v1.z+v1.w*v1.w
                     + v2.x*v2.x+v2.y*v2.y+v2.z*v2.z+v2.w*v2.w
                     + v3.x*v3.x+v3.y*v3.y+v3.z*v3.z+v3.w*v3.w;
            atomicAdd(&s_sqj[jr], pa);
            u16x8 b0, b1;
            b0[0]=f2bf(v0.x); b0[1]=f2bf(v0.y); b0[2]=f2bf(v0.z); b0[3]=f2bf(v0.w);
            b0[4]=f2bf(v1.x); b0[5]=f2bf(v1.y); b0[6]=f2bf(v1.z); b0[7]=f2bf(v1.w);
            b1[0]=f2bf(v2.x); b1[1]=f2bf(v2.y); b1[2]=f2bf(v2.z); b1[3]=f2bf(v2.w);
            b1[4]=f2bf(v3.x); b1[5]=f2bf(v3.y); b1[6]=f2bf(v3.z); b1[7]=f2bf(v3.w);
            int sw = (jr & 7) << 4;
            *(u16x8*)((char*)s_xj + jr * 128 + ((c16 * 2) ^ sw)) = b0;
            *(u16x8*)((char*)s_xj + jr * 128 + ((c16 * 2 + 16) ^ sw)) = b1;
        }
        __syncthreads();
        bf16x8 bfr[2];
        #pragma unroll
        for (int kc = 0; kc < 2; kc++) {
            int row = w * 16 + lo;
            bfr[kc] = *(const bf16x8*)((const char*)s_xj + row * 128 +
                       ((kc * 64 + hi * 16) ^ ((row & 7) << 4)));
        }
        f32x4 acc[2]; acc[0] = (f32x4)0.f; acc[1] = (f32x4)0.f;
        #pragma unroll
        for (int it = 0; it < 2; it++)
            #pragma unroll
            for (int kc = 0; kc < 2; kc++)
                acc[it] = __builtin_amdgcn_mfma_f32_16x16x32_bf16(af[it][kc], bfr[kc], acc[it], 0, 0, 0);
        #pragma unroll
        for (int it = 0; it < 2; it++)
            #pragma unroll
            for (int r = 0; r < 4; r++) {
                int i_s = it * 16 + hi * 4 + r;
                int j_l = w * 16 + lo;
                float pd = fmaxf(s_sqi[i_s] + s_sqj[j_l] - 2.0f * acc[it][r], 0.0f);
                int bin = min((int)(pd * scale), NB - 1);
                atomicAdd(&s_hist[bin], 1u);
            }
    }
    __syncthreads();
    // ---- median scan: 65536 samples -> kq {32767, 32768} ----
    unsigned v[8]; unsigned s = 0;
    #pragma unroll
    for (int b = 0; b < 8; b++) { v[b] = s_hist[tid * 8 + b]; s += v[b]; }
    csum[tid] = s;
    __syncthreads();
    #pragma unroll
    for (int off = 1; off < 256; off <<= 1) {
        unsigned t = (tid >= off) ? csum[tid - off] : 0u;
        __syncthreads();
        csum[tid] += t;
        __syncthreads();
    }
    unsigned incl = csum[tid], excl = incl - s;
    const float binw = PD_RANGE / (float)NB;
    const unsigned kqs[2] = { 32767u, 32768u };
    #pragma unroll
    for (int t = 0; t < 2; t++) {
        unsigned kq = kqs[t];
        if (excl <= kq && kq < incl) {
            unsigned a2 = excl; int bin = -1;
            #pragma unroll
            for (int b = 0; b < 8; b++) {
                unsigned na = a2 + v[b];
                if (bin < 0 && na > kq) bin = tid * 8 + b;
                a2 = na;
            }
            medv[t] = ((float)bin + 0.5f) * binw;
        }
    }
    __syncthreads();
    if (tid == 0) {
        float hh = 0.5f * (medv[0] + medv[1]) / LOG_N + 1e-6f;
        scal_f[0] = 1.0f / hh;
        scal_f[1] = 2.0f / hh;
    }
}

// ---------------- fused SVGD: 16 waves/block (4/SIMD), fence-free, inline epilogue ----------------
__global__ __launch_bounds__(1024, 4) void svgd_k(const float* __restrict__ x,
                                                  char* __restrict__ ws,
                                                  float* __restrict__ out) {
    __shared__ unsigned short s_k[16 * 512];     // 16 KB (intra-wave K shuffle, 16 wave windows)
    __shared__ unsigned short s_c[16 * 512];     // 16 KB
    __shared__ float s_red[2 * 8 * 64];          // 4 KB (cross-wave reduction)
    __shared__ float s_rs[8];
    const unsigned short* XB = (const unsigned short*)(ws + XB_OFF);
    const char* WTb = ws + WT_OFF;
    const char* XTb = ws + XT_OFF;
    const float* SQ = (const float*)(ws + SQ_OFF);
    const float* scal_f = (const float*)(ws + SCAL_OFF);
    int tid = threadIdx.x;
    int i0 = blockIdx.x * 8;
    int lane = tid & 63, w = tid >> 6, lo = lane & 15, hi = lane >> 4;

    for (int q = tid; q < 2 * 8 * 64; q += 1024) s_red[q] = 0.f;
    if (tid < 8) s_rs[tid] = 0.f;

    float inv_hh = scal_f[0], thh = scal_f[1];
    float sqi_r[4];
    #pragma unroll
    for (int r = 0; r < 4; r++) { int il = hi * 4 + r; sqi_r[r] = (il < 8) ? SQ[i0 + il] : 0.0f; }
    bf16x8 af[2];
    #pragma unroll
    for (int kc = 0; kc < 2; kc++)
        af[kc] = (lo < 8) ? *(const bf16x8*)(XB + (i0 + lo) * 64 + kc * 32 + hi * 8) : (bf16x8)0;

    f32x4 a1[4], a2[4], rsv;
    #pragma unroll
    for (int sd = 0; sd < 4; sd++) { a1[sd] = (f32x4)0.f; a2[sd] = (f32x4)0.f; }
    rsv = (f32x4)0.f;
    bf16x8 ones;
    #pragma unroll
    for (int e = 0; e < 8; e++) ones[e] = (short)0x3F80;
    __syncthreads();                              // s_red init visible

    // ---- 4 iters x 512 j (16 waves x 32 j each) ----
    for (int itr = 0; itr < 4; itr++) {
        int jw = itr * 512 + w * 32;              // this wave's 32-j slice
        bf16x8 bS[2][2];
        #pragma unroll
        for (int sj = 0; sj < 2; sj++)
            #pragma unroll
            for (int kc = 0; kc < 2; kc++)
                bS[sj][kc] = *(const bf16x8*)(XB + (jw + sj * 16 + lo) * 64 + kc * 32 + hi * 8);
        float sqj[2];
        sqj[0] = SQ[jw + lo];
        sqj[1] = SQ[jw + 16 + lo];
        int jt = jw >> 7;
        const char* wtb = WTb + jt * 16384;
        const char* xtb = XTb + jt * 16384;
        bf16x8 bW[4], bX[4];
        #pragma unroll
        for (int sd = 0; sd < 4; sd++) {
            int off = (sd * 16 + lo) * 256 + ((jw & 127) * 2) + hi * 16;
            bW[sd] = *(const bf16x8*)(wtb + off);
            bX[sd] = *(const bf16x8*)(xtb + off);
        }
        // S = X_I . X_J^T
        f32x4 sreg[2]; sreg[0] = (f32x4)0.f; sreg[1] = (f32x4)0.f;
        #pragma unroll
        for (int kc = 0; kc < 2; kc++)
            #pragma unroll
            for (int sj = 0; sj < 2; sj++)
                sreg[sj] = __builtin_amdgcn_mfma_f32_16x16x32_bf16(af[kc], bS[sj][kc], sreg[sj], 0, 0, 0);
        // K, C -> bf16 -> LDS (intra-wave re-layout; per-row XOR bijection, reads == own writes)
        #pragma unroll
        for (int sj = 0; sj < 2; sj++) {
            float rq = 1.0f / sqj[sj];
            #pragma unroll
            for (int r = 0; r < 4; r++) {
                int il = hi * 4 + r;
                float dot = sreg[sj][r];
                float pd = fmaxf(sqi_r[r] + sqj[sj] - 2.0f * dot, 0.0f);
                float kv = __expf(-pd * inv_hh);
                float cv = kv * dot * rq;
                int byt = (w * 64 + sj * 32 + lo * 2) ^ ((il & 7) << 4);
                *(unsigned short*)((char*)s_k + il * 1024 + byt) = f2bf(kv);
                *(unsigned short*)((char*)s_c + il * 1024 + byt) = f2bf(cv);
            }
        }
        int bytK = (w * 64 + hi * 16) ^ ((lo & 7) << 4);
        bf16x8 aK = *(const bf16x8*)((const char*)s_k + lo * 1024 + bytK);
        bf16x8 aC = *(const bf16x8*)((const char*)s_c + lo * 1024 + bytK);
        // acc1 += K.W, acc2 += C.X, rs += K.1
        #pragma unroll
        for (int sd = 0; sd < 4; sd++) {
            a1[sd] = __builtin_amdgcn_mfma_f32_16x16x32_bf16(aK, bW[sd], a1[sd], 0, 0, 0);
            a2[sd] = __builtin_amdgcn_mfma_f32_16x16x32_bf16(aC, bX[sd], a2[sd], 0, 0, 0);
        }
        rsv = __builtin_amdgcn_mfma_f32_16x16x32_bf16(aK, ones, rsv, 0, 0, 0);
    }

    // ---- cross-wave reduction (16 waves' disjoint j-slices) ----
    #pragma unroll
    for (int sd = 0; sd < 4; sd++)
        #pragma unroll
        for (int r = 0; r < 4; r++) {
            int il = hi * 4 + r;
            if (il < 8) {
                int dd = sd * 16 + lo;
                atomicAdd(&s_red[il * 64 + dd], a1[sd][r]);
                atomicAdd(&s_red[8 * 64 + il * 64 + dd], a2[sd][r]);
            }
        }
    if (lo == 0) {
        #pragma unroll
        for (int r = 0; r < 4; r++) {
            int il = hi * 4 + r;
            if (il < 8) atomicAdd(&s_rs[il], rsv[r]);
        }
    }
    __syncthreads();

    // ---- inline epilogue: waves 0-7 handle row i0+w, lane = d ----
    if (w < 8) {
        int row = i0 + w;
        float xv = x[row * DIM + lane];
        float sqi = SQ[row];
        float acc1 = s_red[w * 64 + lane];
        float acc2 = s_red[8 * 64 + w * 64 + lane];
        float rs = s_rs[w];
        float inner = acc1 + (rs * xv - acc2) * thh;
        float xin = wred64(xv * inner);
        float gr = inner - xv * ((xin + 63.0f) / sqi);
        float dx = gr * (0.1f / (float)N);
        dx = fminf(fmaxf(dx, -1000.0f), 1000.0f);
        out[row * DIM + lane] = xv + dx;
    }
}

extern "C" void kernel_launch(void* const* d_in, const int* in_sizes, int n_in,
                              void* d_out, int out_size, void* d_ws, size_t ws_size,
                              hipStream_t stream) {
    const float* x  = (const float*)d_in[0];
    const float* mu = (const float*)d_in[1];
    float* out = (float*)d_out;
    char* ws = (char*)d_ws;

    prep_hist_k<<<513, 256, 0, stream>>>(x, mu, ws);
    svgd_k<<<N / 8, 1024, 0, stream>>>(x, ws, out);
}

// Round 14
// 115.104 us; speedup vs baseline: 2.2375x; 1.2152x over previous
//
#include <hip/hip_runtime.h>

#define N 2048
#define DIM 64
#define NB 2048
#define PD_RANGE 1024.0f      // fixed hist range; pd <= 4*max||x||^2 ~ 520 << 1024
#define LOG_N 7.624618986159398f

typedef short bf16x8 __attribute__((ext_vector_type(8)));
typedef float f32x4 __attribute__((ext_vector_type(4)));
typedef unsigned short u16x8 __attribute__((ext_vector_type(8)));

// ws layout (bytes)
#define GHIST_OFF 0           // u32[2048]  (zeroed by prep blocks 0-7)
#define SCAL_OFF  8192        // f32[2]: inv_hh, thh (written by hist_k fan-in)
#define CNTH_OFF  8256        // u32 hist fan-in counter (zeroed by prep block 8)
#define SQ_OFF    8448        // f32[2048]
#define XB_OFF    16640       // bf16 XB[N][64] row-major       (262144)
#define WT_OFF    278784      // bf16 WT[16][64][128] (d-major) (262144)
#define XT_OFF    540928      // bf16 XT[16][64][128]           (262144)

__device__ inline float wred64(float v) {
    #pragma unroll
    for (int m = 32; m; m >>= 1) v += __shfl_xor(v, m, 64);
    return v;
}
__device__ inline unsigned short f2bf(float f) {
    unsigned u = __float_as_uint(f);
    return (unsigned short)((u + 0x7FFFu + ((u >> 16) & 1u)) >> 16);
}

// ---------------- prep: zero hist/counter; sq, w, bf16 X copies ----------------
__global__ __launch_bounds__(256) void prep_k(const float* __restrict__ x,
                                              const float* __restrict__ mu,
                                              char* __restrict__ ws) {
    unsigned short* XB = (unsigned short*)(ws + XB_OFF);
    unsigned short* WT = (unsigned short*)(ws + WT_OFF);
    unsigned short* XT = (unsigned short*)(ws + XT_OFF);
    float* SQ = (float*)(ws + SQ_OFF);
    unsigned* ghist = (unsigned*)(ws + GHIST_OFF);
    if (blockIdx.x < 8) ghist[blockIdx.x * 256 + threadIdx.x] = 0u;
    if (blockIdx.x == 8 && threadIdx.x == 0) *(unsigned*)(ws + CNTH_OFF) = 0u;
    int w = threadIdx.x >> 6, lane = threadIdx.x & 63;
    int j = blockIdx.x * 4 + w;
    float xv = x[j * DIM + lane];
    float sg = mu[lane] - xv;                       // s_grad
    float sq = wred64(xv * xv);
    float xd = wred64(xv * sg);
    float wv = sg - xv * (xd / sq) - xv * (63.0f / sq);  // D_j s_grad + divD_j
    XB[j * DIM + lane] = f2bf(xv);
    int bo = ((j >> 7) * DIM + lane) * 128 + (j & 127);  // [jt][d][jl]
    XT[bo] = f2bf(xv);
    WT[bo] = f2bf(wv);
    if (lane == 0) SQ[j] = sq;
}

// ---------------- histogram (rows subsampled by 4, 1M samples) + fan-in median ----------------
__global__ __launch_bounds__(256) void hist_k(char* __restrict__ ws) {
    __shared__ unsigned short s_xi[128 * 64];
    __shared__ unsigned short s_xj[64 * 64];
    __shared__ float s_sqi[128];
    __shared__ float s_sqj[64];
    __shared__ unsigned s_hist[NB];
    __shared__ unsigned s_flag;
    __shared__ float medv[2];
    const unsigned short* XB = (const unsigned short*)(ws + XB_OFF);
    const float* SQ = (const float*)(ws + SQ_OFF);
    unsigned* ghist = (unsigned*)(ws + GHIST_OFF);
    unsigned* cnth = (unsigned*)(ws + CNTH_OFF);
    float* scal_f = (float*)(ws + SCAL_OFF);
    int tid = threadIdx.x;
    int i0 = (blockIdx.x >> 5) * 128;             // sampled-row base (rows = 4*r)
    int j0 = (blockIdx.x & 31) * 64;
    for (int b = tid; b < NB; b += 256) s_hist[b] = 0u;
    const u16x8* XBv = (const u16x8*)XB;
    #pragma unroll
    for (int q = 0; q < 4; q++) {
        int idx = tid + q * 256; int r = idx >> 3, c = idx & 7;
        u16x8 v = XBv[(4 * (i0 + r)) * 8 + c];
        int byt = (c * 16) ^ ((r & 7) << 4);
        *(u16x8*)((char*)s_xi + r * 128 + byt) = v;
    }
    #pragma unroll
    for (int q = 0; q < 2; q++) {
        int idx = tid + q * 256; int r = idx >> 3, c = idx & 7;
        u16x8 v = XBv[(j0 + r) * 8 + c];
        int byt = (c * 16) ^ ((r & 7) << 4);
        *(u16x8*)((char*)s_xj + r * 128 + byt) = v;
    }
    if (tid < 128) s_sqi[tid] = SQ[4 * (i0 + tid)];
    if (tid >= 128 && tid < 192) s_sqj[tid - 128] = SQ[j0 + tid - 128];
    const float scale = (float)NB / PD_RANGE;
    __syncthreads();
    int lane = tid & 63, w = tid >> 6, lo = lane & 15, hi = lane >> 4;
    f32x4 acc[2][4];
    #pragma unroll
    for (int a = 0; a < 2; a++)
        #pragma unroll
        for (int b = 0; b < 4; b++) acc[a][b] = (f32x4)0.0f;
    #pragma unroll
    for (int kc = 0; kc < 2; kc++) {
        bf16x8 af[2];
        #pragma unroll
        for (int si = 0; si < 2; si++) {
            int row = w * 32 + si * 16 + lo;
            int byt = (kc * 64 + hi * 16) ^ ((row & 7) << 4);
            af[si] = *(const bf16x8*)((const char*)s_xi + row * 128 + byt);
        }
        #pragma unroll
        for (int sj = 0; sj < 4; sj++) {
            int row = sj * 16 + lo;
            int byt = (kc * 64 + hi * 16) ^ ((row & 7) << 4);
            bf16x8 bfr = *(const bf16x8*)((const char*)s_xj + row * 128 + byt);
            #pragma unroll
            for (int si = 0; si < 2; si++)
                acc[si][sj] = __builtin_amdgcn_mfma_f32_16x16x32_bf16(af[si], bfr, acc[si][sj], 0, 0, 0);
        }
    }
    #pragma unroll
    for (int si = 0; si < 2; si++)
        #pragma unroll
        for (int sj = 0; sj < 4; sj++)
            #pragma unroll
            for (int r = 0; r < 4; r++) {
                int il = w * 32 + si * 16 + hi * 4 + r;
                int jl = sj * 16 + lo;
                float pd = fmaxf(s_sqi[il] + s_sqj[jl] - 2.0f * acc[si][sj][r], 0.0f);
                int bin = min((int)(pd * scale), NB - 1);
                atomicAdd(&s_hist[bin], 1u);
            }
    __syncthreads();
    for (int b = tid; b < NB; b += 256) { unsigned v = s_hist[b]; if (v) atomicAdd(&ghist[b], v); }
    // ---- fan-in: last block computes median -> 1/hh, 2/hh ----
    __threadfence();
    if (tid == 0) s_flag = atomicAdd(cnth, 1u);
    __syncthreads();
    if (s_flag == 127u) {
        __threadfence();
        unsigned v[8]; unsigned s = 0;
        #pragma unroll
        for (int b = 0; b < 8; b++) { v[b] = ghist[tid * 8 + b]; s += v[b]; }
        unsigned* csum = s_hist;                    // reuse (post-barrier)
        csum[tid] = s;
        __syncthreads();
        #pragma unroll
        for (int off = 1; off < 256; off <<= 1) {
            unsigned t = (tid >= off) ? csum[tid - off] : 0u;
            __syncthreads();
            csum[tid] += t;
            __syncthreads();
        }
        unsigned incl = csum[tid], excl = incl - s;
        const float binw = PD_RANGE / (float)NB;
        const unsigned kqs[2] = { 524287u, 524288u };  // 2^20/2 - 1, 2^20/2
        #pragma unroll
        for (int t = 0; t < 2; t++) {
            unsigned kq = kqs[t];
            if (excl <= kq && kq < incl) {
                unsigned a2 = excl; int bin = -1;
                #pragma unroll
                for (int b = 0; b < 8; b++) {
                    unsigned na = a2 + v[b];
                    if (bin < 0 && na > kq) bin = tid * 8 + b;
                    a2 = na;
                }
                medv[t] = ((float)bin + 0.5f) * binw;
            }
        }
        __syncthreads();
        if (tid == 0) {
            float hh = 0.5f * (medv[0] + medv[1]) / LOG_N + 1e-6f;
            scal_f[0] = 1.0f / hh;
            scal_f[1] = 2.0f / hh;
        }
    }
}

// ---------------- fused SVGD: 16 waves/block (4/SIMD), fence-free, inline epilogue ----------------
__global__ __launch_bounds__(1024, 4) void svgd_k(const float* __restrict__ x,
                                                  char* __restrict__ ws,
                                                  float* __restrict__ out) {
    __shared__ unsigned short s_k[16 * 512];     // 16 KB (intra-wave K shuffle, 16 wave windows)
    __shared__ unsigned short s_c[16 * 512];     // 16 KB
    __shared__ float s_red[2 * 8 * 64];          // 4 KB (cross-wave reduction)
    __shared__ float s_rs[8];
    const unsigned short* XB = (const unsigned short*)(ws + XB_OFF);
    const char* WTb = ws + WT_OFF;
    const char* XTb = ws + XT_OFF;
    const float* SQ = (const float*)(ws + SQ_OFF);
    const float* scal_f = (const float*)(ws + SCAL_OFF);
    int tid = threadIdx.x;
    int i0 = blockIdx.x * 8;
    int lane = tid & 63, w = tid >> 6, lo = lane & 15, hi = lane >> 4;

    for (int q = tid; q < 2 * 8 * 64; q += 1024) s_red[q] = 0.f;
    if (tid < 8) s_rs[tid] = 0.f;

    float inv_hh = scal_f[0], thh = scal_f[1];
    float sqi_r[4];
    #pragma unroll
    for (int r = 0; r < 4; r++) { int il = hi * 4 + r; sqi_r[r] = (il < 8) ? SQ[i0 + il] : 0.0f; }
    bf16x8 af[2];
    #pragma unroll
    for (int kc = 0; kc < 2; kc++)
        af[kc] = (lo < 8) ? *(const bf16x8*)(XB + (i0 + lo) * 64 + kc * 32 + hi * 8) : (bf16x8)0;

    f32x4 a1[4], a2[4], rsv;
    #pragma unroll
    for (int sd = 0; sd < 4; sd++) { a1[sd] = (f32x4)0.f; a2[sd] = (f32x4)0.f; }
    rsv = (f32x4)0.f;
    bf16x8 ones;
    #pragma unroll
    for (int e = 0; e < 8; e++) ones[e] = (short)0x3F80;
    __syncthreads();                              // s_red init visible

    // ---- 4 iters x 512 j (16 waves x 32 j each) ----
    for (int itr = 0; itr < 4; itr++) {
        int jw = itr * 512 + w * 32;              // this wave's 32-j slice
        bf16x8 bS[2][2];
        #pragma unroll
        for (int sj = 0; sj < 2; sj++)
            #pragma unroll
            for (int kc = 0; kc < 2; kc++)
                bS[sj][kc] = *(const bf16x8*)(XB + (jw + sj * 16 + lo) * 64 + kc * 32 + hi * 8);
        float sqj[2];
        sqj[0] = SQ[jw + lo];
        sqj[1] = SQ[jw + 16 + lo];
        int jt = jw >> 7;
        const char* wtb = WTb + jt * 16384;
        const char* xtb = XTb + jt * 16384;
        bf16x8 bW[4], bX[4];
        #pragma unroll
        for (int sd = 0; sd < 4; sd++) {
            int off = (sd * 16 + lo) * 256 + ((jw & 127) * 2) + hi * 16;
            bW[sd] = *(const bf16x8*)(wtb + off);
            bX[sd] = *(const bf16x8*)(xtb + off);
        }
        // S = X_I . X_J^T
        f32x4 sreg[2]; sreg[0] = (f32x4)0.f; sreg[1] = (f32x4)0.f;
        #pragma unroll
        for (int kc = 0; kc < 2; kc++)
            #pragma unroll
            for (int sj = 0; sj < 2; sj++)
                sreg[sj] = __builtin_amdgcn_mfma_f32_16x16x32_bf16(af[kc], bS[sj][kc], sreg[sj], 0, 0, 0);
        // K, C -> bf16 -> LDS (intra-wave re-layout; per-row XOR bijection, reads == own writes)
        #pragma unroll
        for (int sj = 0; sj < 2; sj++) {
            float rq = 1.0f / sqj[sj];
            #pragma unroll
            for (int r = 0; r < 4; r++) {
                int il = hi * 4 + r;
                float dot = sreg[sj][r];
                float pd = fmaxf(sqi_r[r] + sqj[sj] - 2.0f * dot, 0.0f);
                float kv = __expf(-pd * inv_hh);
                float cv = kv * dot * rq;
                int byt = (w * 64 + sj * 32 + lo * 2) ^ ((il & 7) << 4);
                *(unsigned short*)((char*)s_k + il * 1024 + byt) = f2bf(kv);
                *(unsigned short*)((char*)s_c + il * 1024 + byt) = f2bf(cv);
            }
        }
        int bytK = (w * 64 + hi * 16) ^ ((lo & 7) << 4);
        bf16x8 aK = *(const bf16x8*)((const char*)s_k + lo * 1024 + bytK);
        bf16x8 aC = *(const bf16x8*)((const char*)s_c + lo * 1024 + bytK);
        // acc1 += K.W, acc2 += C.X, rs += K.1
        #pragma unroll
        for (int sd = 0; sd < 4; sd++) {
            a1[sd] = __builtin_amdgcn_mfma_f32_16x16x32_bf16(aK, bW[sd], a1[sd], 0, 0, 0);
            a2[sd] = __builtin_amdgcn_mfma_f32_16x16x32_bf16(aC, bX[sd], a2[sd], 0, 0, 0);
        }
        rsv = __builtin_amdgcn_mfma_f32_16x16x32_bf16(aK, ones, rsv, 0, 0, 0);
    }

    // ---- cross-wave reduction (16 waves' disjoint j-slices) ----
    #pragma unroll
    for (int sd = 0; sd < 4; sd++)
        #pragma unroll
        for (int r = 0; r < 4; r++) {
            int il = hi * 4 + r;
            if (il < 8) {
                int dd = sd * 16 + lo;
                atomicAdd(&s_red[il * 64 + dd], a1[sd][r]);
                atomicAdd(&s_red[8 * 64 + il * 64 + dd], a2[sd][r]);
            }
        }
    if (lo == 0) {
        #pragma unroll
        for (int r = 0; r < 4; r++) {
            int il = hi * 4 + r;
            if (il < 8) atomicAdd(&s_rs[il], rsv[r]);
        }
    }
    __syncthreads();

    // ---- inline epilogue: waves 0-7 handle row i0+w, lane = d ----
    if (w < 8) {
        int row = i0 + w;
        float xv = x[row * DIM + lane];
        float sqi = SQ[row];
        float acc1 = s_red[w * 64 + lane];
        float acc2 = s_red[8 * 64 + w * 64 + lane];
        float rs = s_rs[w];
        float inner = acc1 + (rs * xv - acc2) * thh;
        float xin = wred64(xv * inner);
        float gr = inner - xv * ((xin + 63.0f) / sqi);
        float dx = gr * (0.1f / (float)N);
        dx = fminf(fmaxf(dx, -1000.0f), 1000.0f);
        out[row * DIM + lane] = xv + dx;
    }
}

extern "C" void kernel_launch(void* const* d_in, const int* in_sizes, int n_in,
                              void* d_out, int out_size, void* d_ws, size_t ws_size,
                              hipStream_t stream) {
    const float* x  = (const float*)d_in[0];
    const float* mu = (const float*)d_in[1];
    float* out = (float*)d_out;
    char* ws = (char*)d_ws;

    prep_k<<<N / 4, 256, 0, stream>>>(x, mu, ws);
    hist_k<<<(512 / 128) * (N / 64), 256, 0, stream>>>(ws);
    svgd_k<<<N / 8, 1024, 0, stream>>>(x, ws, out);
}

// Round 15
// 104.938 us; speedup vs baseline: 2.4543x; 1.0969x over previous
//
#include <hip/hip_runtime.h>

#define N 2048
#define DIM 64
#define NB 2048
#define PD_RANGE 1024.0f      // fixed hist range; pd <= 4*max||x||^2 ~ 520 << 1024
#define LOG_N 7.624618986159398f

typedef short bf16x8 __attribute__((ext_vector_type(8)));
typedef float f32x4 __attribute__((ext_vector_type(4)));
typedef unsigned short u16x8 __attribute__((ext_vector_type(8)));

// ws layout (bytes)
#define GHIST_OFF 0           // u32[2048]  (zeroed by prep blocks 0-7)
#define SCAL_OFF  8192        // f32[2]: inv_hh, thh (written by hist_k fan-in)
#define CNTH_OFF  8256        // u32 hist fan-in counter (zeroed by prep block 8)
#define SQ_OFF    8448        // f32[2048]
#define XB_OFF    16640       // bf16 XB[N][64] row-major (hist + af)     (262144)
#define XS_OFF    278784      // bf16 XS[N/16][2][16][32] wave-contig X   (262144)
#define WT_OFF    540928      // bf16 WT4[16][4][64][32] wave-contig W^T  (262144)
#define XT_OFF    803072      // bf16 XT4[16][4][64][32] wave-contig X^T  (262144)

__device__ inline float wred64(float v) {
    #pragma unroll
    for (int m = 32; m; m >>= 1) v += __shfl_xor(v, m, 64);
    return v;
}
__device__ inline unsigned short f2bf(float f) {
    unsigned u = __float_as_uint(f);
    return (unsigned short)((u + 0x7FFFu + ((u >> 16) & 1u)) >> 16);
}

// ---------------- prep: zero hist/counter; sq, w, bf16 tables ----------------
__global__ __launch_bounds__(256) void prep_k(const float* __restrict__ x,
                                              const float* __restrict__ mu,
                                              char* __restrict__ ws) {
    unsigned short* XB = (unsigned short*)(ws + XB_OFF);
    unsigned short* XS = (unsigned short*)(ws + XS_OFF);
    unsigned short* WT = (unsigned short*)(ws + WT_OFF);
    unsigned short* XT = (unsigned short*)(ws + XT_OFF);
    float* SQ = (float*)(ws + SQ_OFF);
    unsigned* ghist = (unsigned*)(ws + GHIST_OFF);
    if (blockIdx.x < 8) ghist[blockIdx.x * 256 + threadIdx.x] = 0u;
    if (blockIdx.x == 8 && threadIdx.x == 0) *(unsigned*)(ws + CNTH_OFF) = 0u;
    int w = threadIdx.x >> 6, lane = threadIdx.x & 63;
    int j = blockIdx.x * 4 + w;
    float xv = x[j * DIM + lane];
    float sg = mu[lane] - xv;                       // s_grad
    float sq = wred64(xv * xv);
    float xd = wred64(xv * sg);
    float wv = sg - xv * (xd / sq) - xv * (63.0f / sq);  // D_j s_grad + divD_j
    unsigned short xb = f2bf(xv);
    XB[j * DIM + lane] = xb;
    // wave-contiguous X for bS: XS[(g*2+kc)*512 + (j&15)*32 + (d&31)]
    XS[((j >> 4) * 2 + (lane >> 5)) * 512 + (j & 15) * 32 + (lane & 31)] = xb;
    // wave-contiguous W^T/X^T: [jt][c][d][jj]
    int bo = (j >> 7) * 8192 + ((j >> 5) & 3) * 2048 + lane * 32 + (j & 31);
    XT[bo] = xb;
    WT[bo] = f2bf(wv);
    if (lane == 0) SQ[j] = sq;
}

// ---------------- histogram (rows subsampled by 4, 1M samples) + fan-in median ----------------
__global__ __launch_bounds__(256) void hist_k(char* __restrict__ ws) {
    __shared__ unsigned short s_xi[128 * 64];
    __shared__ unsigned short s_xj[64 * 64];
    __shared__ float s_sqi[128];
    __shared__ float s_sqj[64];
    __shared__ unsigned s_hist[NB];
    __shared__ unsigned s_flag;
    __shared__ float medv[2];
    const unsigned short* XB = (const unsigned short*)(ws + XB_OFF);
    const float* SQ = (const float*)(ws + SQ_OFF);
    unsigned* ghist = (unsigned*)(ws + GHIST_OFF);
    unsigned* cnth = (unsigned*)(ws + CNTH_OFF);
    float* scal_f = (float*)(ws + SCAL_OFF);
    int tid = threadIdx.x;
    int i0 = (blockIdx.x >> 5) * 128;             // sampled-row base (rows = 4*r)
    int j0 = (blockIdx.x & 31) * 64;
    for (int b = tid; b < NB; b += 256) s_hist[b] = 0u;
    const u16x8* XBv = (const u16x8*)XB;
    #pragma unroll
    for (int q = 0; q < 4; q++) {
        int idx = tid + q * 256; int r = idx >> 3, c = idx & 7;
        u16x8 v = XBv[(4 * (i0 + r)) * 8 + c];
        int byt = (c * 16) ^ ((r & 7) << 4);
        *(u16x8*)((char*)s_xi + r * 128 + byt) = v;
    }
    #pragma unroll
    for (int q = 0; q < 2; q++) {
        int idx = tid + q * 256; int r = idx >> 3, c = idx & 7;
        u16x8 v = XBv[(j0 + r) * 8 + c];
        int byt = (c * 16) ^ ((r & 7) << 4);
        *(u16x8*)((char*)s_xj + r * 128 + byt) = v;
    }
    if (tid < 128) s_sqi[tid] = SQ[4 * (i0 + tid)];
    if (tid >= 128 && tid < 192) s_sqj[tid - 128] = SQ[j0 + tid - 128];
    const float scale = (float)NB / PD_RANGE;
    __syncthreads();
    int lane = tid & 63, w = tid >> 6, lo = lane & 15, hi = lane >> 4;
    f32x4 acc[2][4];
    #pragma unroll
    for (int a = 0; a < 2; a++)
        #pragma unroll
        for (int b = 0; b < 4; b++) acc[a][b] = (f32x4)0.0f;
    #pragma unroll
    for (int kc = 0; kc < 2; kc++) {
        bf16x8 af[2];
        #pragma unroll
        for (int si = 0; si < 2; si++) {
            int row = w * 32 + si * 16 + lo;
            int byt = (kc * 64 + hi * 16) ^ ((row & 7) << 4);
            af[si] = *(const bf16x8*)((const char*)s_xi + row * 128 + byt);
        }
        #pragma unroll
        for (int sj = 0; sj < 4; sj++) {
            int row = sj * 16 + lo;
            int byt = (kc * 64 + hi * 16) ^ ((row & 7) << 4);
            bf16x8 bfr = *(const bf16x8*)((const char*)s_xj + row * 128 + byt);
            #pragma unroll
            for (int si = 0; si < 2; si++)
                acc[si][sj] = __builtin_amdgcn_mfma_f32_16x16x32_bf16(af[si], bfr, acc[si][sj], 0, 0, 0);
        }
    }
    #pragma unroll
    for (int si = 0; si < 2; si++)
        #pragma unroll
        for (int sj = 0; sj < 4; sj++)
            #pragma unroll
            for (int r = 0; r < 4; r++) {
                int il = w * 32 + si * 16 + hi * 4 + r;
                int jl = sj * 16 + lo;
                float pd = fmaxf(s_sqi[il] + s_sqj[jl] - 2.0f * acc[si][sj][r], 0.0f);
                int bin = min((int)(pd * scale), NB - 1);
                atomicAdd(&s_hist[bin], 1u);
            }
    __syncthreads();
    for (int b = tid; b < NB; b += 256) { unsigned v = s_hist[b]; if (v) atomicAdd(&ghist[b], v); }
    // ---- fan-in: last block computes median -> 1/hh, 2/hh ----
    __threadfence();
    if (tid == 0) s_flag = atomicAdd(cnth, 1u);
    __syncthreads();
    if (s_flag == 127u) {
        __threadfence();
        unsigned v[8]; unsigned s = 0;
        #pragma unroll
        for (int b = 0; b < 8; b++) { v[b] = ghist[tid * 8 + b]; s += v[b]; }
        unsigned* csum = s_hist;                    // reuse (post-barrier)
        csum[tid] = s;
        __syncthreads();
        #pragma unroll
        for (int off = 1; off < 256; off <<= 1) {
            unsigned t = (tid >= off) ? csum[tid - off] : 0u;
            __syncthreads();
            csum[tid] += t;
            __syncthreads();
        }
        unsigned incl = csum[tid], excl = incl - s;
        const float binw = PD_RANGE / (float)NB;
        const unsigned kqs[2] = { 524287u, 524288u };  // 2^20/2 - 1, 2^20/2
        #pragma unroll
        for (int t = 0; t < 2; t++) {
            unsigned kq = kqs[t];
            if (excl <= kq && kq < incl) {
                unsigned a2 = excl; int bin = -1;
                #pragma unroll
                for (int b = 0; b < 8; b++) {
                    unsigned na = a2 + v[b];
                    if (bin < 0 && na > kq) bin = tid * 8 + b;
                    a2 = na;
                }
                medv[t] = ((float)bin + 0.5f) * binw;
            }
        }
        __syncthreads();
        if (tid == 0) {
            float hh = 0.5f * (medv[0] + medv[1]) / LOG_N + 1e-6f;
            scal_f[0] = 1.0f / hh;
            scal_f[1] = 2.0f / hh;
        }
    }
}

// ---------------- fused SVGD: 16 waves/block, all hot loads lane-contiguous 1KB ----------------
__global__ __launch_bounds__(1024, 4) void svgd_k(const float* __restrict__ x,
                                                  char* __restrict__ ws,
                                                  float* __restrict__ out) {
    __shared__ unsigned short s_k[16 * 512];     // 16 KB (intra-wave K shuffle, 16 wave windows)
    __shared__ unsigned short s_c[16 * 512];     // 16 KB
    __shared__ float s_red[2 * 8 * 64];          // 4 KB (cross-wave reduction)
    __shared__ float s_rs[8];
    const unsigned short* XB = (const unsigned short*)(ws + XB_OFF);
    const unsigned short* XS = (const unsigned short*)(ws + XS_OFF);
    const char* WTb = ws + WT_OFF;
    const char* XTb = ws + XT_OFF;
    const float* SQ = (const float*)(ws + SQ_OFF);
    const float* scal_f = (const float*)(ws + SCAL_OFF);
    int tid = threadIdx.x;
    int i0 = blockIdx.x * 8;
    int lane = tid & 63, w = tid >> 6, lo = lane & 15, hi = lane >> 4;

    for (int q = tid; q < 2 * 8 * 64; q += 1024) s_red[q] = 0.f;
    if (tid < 8) s_rs[tid] = 0.f;

    float inv_hh = scal_f[0], thh = scal_f[1];
    float sqi_r[4];
    #pragma unroll
    for (int r = 0; r < 4; r++) { int il = hi * 4 + r; sqi_r[r] = (il < 8) ? SQ[i0 + il] : 0.0f; }
    bf16x8 af[2];
    #pragma unroll
    for (int kc = 0; kc < 2; kc++)
        af[kc] = (lo < 8) ? *(const bf16x8*)(XB + (i0 + lo) * 64 + kc * 32 + hi * 8) : (bf16x8)0;

    f32x4 a1[4], a2[4], rsv;
    #pragma unroll
    for (int sd = 0; sd < 4; sd++) { a1[sd] = (f32x4)0.f; a2[sd] = (f32x4)0.f; }
    rsv = (f32x4)0.f;
    bf16x8 ones;
    #pragma unroll
    for (int e = 0; e < 8; e++) ones[e] = (short)0x3F80;
    __syncthreads();                              // s_red init visible

    // ---- 4 iters x 512 j (16 waves x 32 j each); every load = lane-contiguous 1KB ----
    for (int itr = 0; itr < 4; itr++) {
        int jw = itr * 512 + w * 32;              // this wave's 32-j slice (32-aligned)
        bf16x8 bS[2][2];
        #pragma unroll
        for (int sj = 0; sj < 2; sj++) {
            int g = (jw >> 4) + sj;
            #pragma unroll
            for (int kc = 0; kc < 2; kc++)
                bS[sj][kc] = *(const bf16x8*)(XS + (g * 2 + kc) * 512 + lo * 32 + hi * 8);
        }
        float sqj[2];
        sqj[0] = SQ[jw + lo];
        sqj[1] = SQ[jw + 16 + lo];
        const char* wtb = WTb + (jw >> 7) * 16384 + ((jw >> 5) & 3) * 4096;
        const char* xtb = XTb + (jw >> 7) * 16384 + ((jw >> 5) & 3) * 4096;
        bf16x8 bW[4], bX[4];
        #pragma unroll
        for (int sd = 0; sd < 4; sd++) {
            int off = (sd * 16 + lo) * 64 + hi * 16;
            bW[sd] = *(const bf16x8*)(wtb + off);
            bX[sd] = *(const bf16x8*)(xtb + off);
        }
        // S = X_I . X_J^T
        f32x4 sreg[2]; sreg[0] = (f32x4)0.f; sreg[1] = (f32x4)0.f;
        #pragma unroll
        for (int kc = 0; kc < 2; kc++)
            #pragma unroll
            for (int sj = 0; sj < 2; sj++)
                sreg[sj] = __builtin_amdgcn_mfma_f32_16x16x32_bf16(af[kc], bS[sj][kc], sreg[sj], 0, 0, 0);
        // K, C -> bf16 -> LDS (intra-wave re-layout; per-row XOR bijection, reads == own writes)
        #pragma unroll
        for (int sj = 0; sj < 2; sj++) {
            float rq = 1.0f / sqj[sj];
            #pragma unroll
            for (int r = 0; r < 4; r++) {
                int il = hi * 4 + r;
                float dot = sreg[sj][r];
                float pd = fmaxf(sqi_r[r] + sqj[sj] - 2.0f * dot, 0.0f);
                float kv = __expf(-pd * inv_hh);
                float cv = kv * dot * rq;
                int byt = (w * 64 + sj * 32 + lo * 2) ^ ((il & 7) << 4);
                *(unsigned short*)((char*)s_k + il * 1024 + byt) = f2bf(kv);
                *(unsigned short*)((char*)s_c + il * 1024 + byt) = f2bf(cv);
            }
        }
        int bytK = (w * 64 + hi * 16) ^ ((lo & 7) << 4);
        bf16x8 aK = *(const bf16x8*)((const char*)s_k + lo * 1024 + bytK);
        bf16x8 aC = *(const bf16x8*)((const char*)s_c + lo * 1024 + bytK);
        // acc1 += K.W, acc2 += C.X, rs += K.1
        #pragma unroll
        for (int sd = 0; sd < 4; sd++) {
            a1[sd] = __builtin_amdgcn_mfma_f32_16x16x32_bf16(aK, bW[sd], a1[sd], 0, 0, 0);
            a2[sd] = __builtin_amdgcn_mfma_f32_16x16x32_bf16(aC, bX[sd], a2[sd], 0, 0, 0);
        }
        rsv = __builtin_amdgcn_mfma_f32_16x16x32_bf16(aK, ones, rsv, 0, 0, 0);
    }

    // ---- cross-wave reduction (16 waves' disjoint j-slices) ----
    #pragma unroll
    for (int sd = 0; sd < 4; sd++)
        #pragma unroll
        for (int r = 0; r < 4; r++) {
            int il = hi * 4 + r;
            if (il < 8) {
                int dd = sd * 16 + lo;
                atomicAdd(&s_red[il * 64 + dd], a1[sd][r]);
                atomicAdd(&s_red[8 * 64 + il * 64 + dd], a2[sd][r]);
            }
        }
    if (lo == 0) {
        #pragma unroll
        for (int r = 0; r < 4; r++) {
            int il = hi * 4 + r;
            if (il < 8) atomicAdd(&s_rs[il], rsv[r]);
        }
    }
    __syncthreads();

    // ---- inline epilogue: waves 0-7 handle row i0+w, lane = d ----
    if (w < 8) {
        int row = i0 + w;
        float xv = x[row * DIM + lane];
        float sqi = SQ[row];
        float acc1 = s_red[w * 64 + lane];
        float acc2 = s_red[8 * 64 + w * 64 + lane];
        float rs = s_rs[w];
        float inner = acc1 + (rs * xv - acc2) * thh;
        float xin = wred64(xv * inner);
        float gr = inner - xv * ((xin + 63.0f) / sqi);
        float dx = gr * (0.1f / (float)N);
        dx = fminf(fmaxf(dx, -1000.0f), 1000.0f);
        out[row * DIM + lane] = xv + dx;
    }
}

extern "C" void kernel_launch(void* const* d_in, const int* in_sizes, int n_in,
                              void* d_out, int out_size, void* d_ws, size_t ws_size,
                              hipStream_t stream) {
    const float* x  = (const float*)d_in[0];
    const float* mu = (const float*)d_in[1];
    float* out = (float*)d_out;
    char* ws = (char*)d_ws;

    prep_k<<<N / 4, 256, 0, stream>>>(x, mu, ws);
    hist_k<<<(512 / 128) * (N / 64), 256, 0, stream>>>(ws);
    svgd_k<<<N / 8, 1024, 0, stream>>>(x, ws, out);
}